// Round 5
// baseline (826.137 us; speedup 1.0000x reference)
//
#include <hip/hip_runtime.h>

// ---- problem dims (fixed) ----
#define T_TOK 8192      // B*S
#define DMODEL 1024
#define NEXP 8
#define TOPK 2
#define HID 4096
#define NPAIR (T_TOK*TOPK)   // 16384
#define BM 128
#define BN 128
#define BK 32
#define MAXT (NPAIR/BM + NEXP)   // 136 row-tiles upper bound

typedef unsigned short u16;
typedef unsigned int u32;
typedef short s16x8 __attribute__((ext_vector_type(8)));
typedef float f32x4 __attribute__((ext_vector_type(4)));

// fp32 -> bf16 round-to-nearest-even
__device__ __forceinline__ u16 f2b(float f) {
    union { float f; unsigned int u; } v; v.f = f;
    return (u16)((v.u + 0x7fffu + ((v.u >> 16) & 1u)) >> 16);
}

__device__ __forceinline__ s16x8 cvt8(float4 f0, float4 f1) {
    s16x8 o;
    o[0]=(short)f2b(f0.x); o[1]=(short)f2b(f0.y); o[2]=(short)f2b(f0.z); o[3]=(short)f2b(f0.w);
    o[4]=(short)f2b(f1.x); o[5]=(short)f2b(f1.y); o[6]=(short)f2b(f1.z); o[7]=(short)f2b(f1.w);
    return o;
}

// async global->LDS, 16B per lane; LDS dest linear in lane order
__device__ __forceinline__ void gload16(const void* g, void* l) {
    __builtin_amdgcn_global_load_lds(
        (const __attribute__((address_space(1))) unsigned int*)g,
        (__attribute__((address_space(3))) unsigned int*)l, 16, 0, 0);
}

// tanh-form gelu, exp/rcp in HW
__device__ __forceinline__ float gelu_fast(float v) {
    float y = 0.7978845608028654f * v * fmaf(0.044715f * v, v, 1.0f);
    float t = -2.8853900817779268f * y;   // -2y * log2(e)
    float z, r;
    asm("v_exp_f32 %0, %1" : "=v"(z) : "v"(t));
    float den = 1.0f + z;
    asm("v_rcp_f32 %0, %1" : "=v"(r) : "v"(den));
    return v * r;
}

// m204 bijective XCD swizzle over nact active blocks
__device__ __forceinline__ int xcd_swz(int bid, int nact) {
    int q = nact >> 3, r = nact & 7;
    int xcd = bid & 7, i = bid >> 3;
    return (xcd < r ? xcd * (q + 1) : r * (q + 1) + (xcd - r) * q) + i;
}

// ---------------- fp32 -> bf16 conversion ----------------
__global__ __launch_bounds__(256) void cvt_kernel(const float* __restrict__ in,
                                                  u16* __restrict__ out, long n8) {
    long stride = (long)gridDim.x * 256;
    for (long i = (long)blockIdx.x * 256 + threadIdx.x; i < n8; i += stride) {
        const float4* p = (const float4*)(in + i * 8);
        float4 f0 = p[0], f1 = p[1];
        *(s16x8*)(out + i * 8) = cvt8(f0, f1);
    }
}

// ---------------- router (fp32; selection must match reference) ----------------
__global__ __launch_bounds__(256) void router_kernel(
    const float* __restrict__ x, const float* __restrict__ Wr, const float* __restrict__ br,
    int* __restrict__ topi, float* __restrict__ topw, int* __restrict__ cnt)
{
    __shared__ float WrS[NEXP * DMODEL];
    int tid = threadIdx.x;
    const float4* Wr4 = (const float4*)Wr;
    float4* WrS4 = (float4*)WrS;
    for (int i = tid; i < NEXP * DMODEL / 4; i += 256) WrS4[i] = Wr4[i];
    __syncthreads();

    int wid = tid >> 6, lane = tid & 63;
    int t = blockIdx.x * 4 + wid;
    const float* xr = x + (size_t)t * DMODEL;

    float acc[NEXP];
#pragma unroll
    for (int e = 0; e < NEXP; ++e) acc[e] = 0.f;
    for (int i = lane; i < DMODEL; i += 64) {
        float xv = xr[i];
#pragma unroll
        for (int e = 0; e < NEXP; ++e) acc[e] = fmaf(xv, WrS[e * DMODEL + i], acc[e]);
    }
#pragma unroll
    for (int e = 0; e < NEXP; ++e) {
        float v = acc[e];
#pragma unroll
        for (int off = 32; off > 0; off >>= 1) v += __shfl_xor(v, off);
        acc[e] = v;
    }
    if (lane == 0) {
        float lg[NEXP];
#pragma unroll
        for (int e = 0; e < NEXP; ++e) lg[e] = acc[e] + br[e];
        int i1 = 0;
#pragma unroll
        for (int e = 1; e < NEXP; ++e) if (lg[e] > lg[i1]) i1 = e;
        int i2 = (i1 == 0) ? 1 : 0;
#pragma unroll
        for (int e = 0; e < NEXP; ++e) if (e != i1 && lg[e] > lg[i2]) i2 = e;
        float e2 = expf(lg[i2] - lg[i1]);
        float s = 1.f + e2;
        topi[t * 2] = i1;  topi[t * 2 + 1] = i2;
        topw[t * 2] = 1.f / s;  topw[t * 2 + 1] = e2 / s;
        atomicAdd(&cnt[i1], 1);
        atomicAdd(&cnt[i2], 1);
    }
}

// offsets + compact tile table + tile count
__global__ void offsets_kernel(const int* __restrict__ cnt, int* __restrict__ offs,
                               u32* __restrict__ table, int* __restrict__ meta) {
    if (threadIdx.x == 0 && blockIdx.x == 0) {
        int a = 0;
        for (int e = 0; e < NEXP; ++e) { offs[e] = a; a += cnt[e]; }
        offs[NEXP] = a;
        int nt = 0;
        for (int e = 0; e < NEXP; ++e)
            for (int r0 = 0; r0 < cnt[e]; r0 += BM)
                table[nt++] = ((u32)e << 20) | (u32)r0;
        meta[0] = nt;
    }
}

// wave-aggregated scatter
__global__ __launch_bounds__(256) void scatter_kernel(
    const int* __restrict__ topi, const float* __restrict__ topw,
    const int* __restrict__ offs, int* __restrict__ fill,
    int* __restrict__ tok, float* __restrict__ wgt)
{
    int t = blockIdx.x * 256 + threadIdx.x;
    int lane = threadIdx.x & 63;
#pragma unroll
    for (int s = 0; s < TOPK; ++s) {
        int e = topi[t * 2 + s];
        float w = topw[t * 2 + s];
#pragma unroll
        for (int ex = 0; ex < NEXP; ++ex) {
            unsigned long long m = __ballot(e == ex);
            if (e == ex) {
                int ldr = (int)__ffsll((unsigned long long)m) - 1;
                int base = 0;
                if (lane == ldr) base = atomicAdd(&fill[ex], (int)__popcll(m));
                base = __shfl(base, ldr);
                int mypos = base + (int)__popcll(m & ((1ull << lane) - 1ull));
                int p = offs[ex] + mypos;
                tok[p] = t;
                wgt[p] = w;
            }
        }
    }
}

// ---- depth-2 prefetch K-loop machinery ----
// [128][32] u16 tiles; 4-slot rows (8 elems each), slot XOR (row&3) swizzle.
// Staging: thread chunk c covers idx=c*256+tid -> row=idx>>2, lds slot=idx&3,
// source slot pre-swizzled = (idx&3)^(row&3). LDS dest is linear.
#define STAGE(Ad, Bd, kt) do {                                              \
    gload16(Agp + aoff0 + (size_t)(kt), (char*)(Ad) + tid * 16);            \
    gload16(Agp + aoff1 + (size_t)(kt), (char*)(Ad) + (256 + tid) * 16);    \
    gload16(Bgp + boff0 + (size_t)(kt), (char*)(Bd) + tid * 16);            \
    gload16(Bgp + boff1 + (size_t)(kt), (char*)(Bd) + (256 + tid) * 16);    \
} while (0)

#define COMPUTE(Ab, Bb) do {                                                \
    s16x8 av[4], bv[4];                                                     \
    int kslot = lane >> 4;                                                  \
    _Pragma("unroll") for (int mi = 0; mi < 4; ++mi) {                      \
        int rr = wm + mi * 16 + (lane & 15);                                \
        av[mi] = *(const s16x8*)((Ab) + rr * 32 + ((kslot ^ (rr & 3)) * 8)); } \
    _Pragma("unroll") for (int ni = 0; ni < 4; ++ni) {                      \
        int rr = wn + ni * 16 + (lane & 15);                                \
        bv[ni] = *(const s16x8*)((Bb) + rr * 32 + ((kslot ^ (rr & 3)) * 8)); } \
    _Pragma("unroll") for (int mi = 0; mi < 4; ++mi)                        \
    _Pragma("unroll") for (int ni = 0; ni < 4; ++ni)                        \
        acc[mi][ni] = __builtin_amdgcn_mfma_f32_16x16x32_bf16(av[mi], bv[ni], acc[mi][ni], 0, 0, 0); \
} while (0)

#define VMW8() asm volatile("s_waitcnt vmcnt(8)" ::: "memory")
#define VMW4() asm volatile("s_waitcnt vmcnt(4)" ::: "memory")
#define VMW0() asm volatile("s_waitcnt vmcnt(0)" ::: "memory")
// raw barrier (no compiler vmcnt(0) drain) + compiler-level memory fence
#define BAR()  do { __builtin_amdgcn_s_barrier(); asm volatile("" ::: "memory"); } while (0)

#define ITER_S(Ac, Bc, Asd, Bsd, sidx) do {   /* steady: stage 2 ahead */   \
    STAGE(Asd, Bsd, (sidx) * BK);                                           \
    VMW8(); BAR();                                                          \
    COMPUTE(Ac, Bc);                                                        \
} while (0)

#define PIPELINE_LOOP(NT) do {                                              \
    STAGE(A0s, B0s, 0);                                                     \
    STAGE(A1s, B1s, BK);                                                    \
    for (int t = 0; t < (NT) - 4; t += 4) {                                 \
        ITER_S(A0s, B0s, A2s, B2s, t + 2);                                  \
        ITER_S(A1s, B1s, A3s, B3s, t + 3);                                  \
        ITER_S(A2s, B2s, A0s, B0s, t + 4);                                  \
        ITER_S(A3s, B3s, A1s, B1s, t + 5);                                  \
    }                                                                       \
    ITER_S(A0s, B0s, A2s, B2s, (NT) - 2);                                   \
    ITER_S(A1s, B1s, A3s, B3s, (NT) - 1);                                   \
    VMW4(); BAR(); COMPUTE(A2s, B2s);                                       \
    VMW0(); BAR(); COMPUTE(A3s, B3s);                                       \
} while (0)

#define GEMM_SHARED_DECLS                                                   \
    __shared__ __align__(16) u16 A0s[BM * BK];                              \
    __shared__ __align__(16) u16 A1s[BM * BK];                              \
    __shared__ __align__(16) u16 A2s[BM * BK];                              \
    __shared__ __align__(16) u16 A3s[BM * BK];                              \
    __shared__ __align__(16) u16 B0s[BN * BK];                              \
    __shared__ __align__(16) u16 B1s[BN * BK];                              \
    __shared__ __align__(16) u16 B2s[BN * BK];                              \
    __shared__ __align__(16) u16 B3s[BN * BK];

// GEMM1: H1[p, n] = gelu( sum_d xb[tok[p], d] * W1b[e, n, d] + b1[e, n] )
__global__ __launch_bounds__(256) void gemm1_kernel(
    const u16* __restrict__ xb, const u16* __restrict__ W1b, const float* __restrict__ b1,
    const int* __restrict__ tok, const int* __restrict__ cnt, const int* __restrict__ offs,
    const u32* __restrict__ table, const int* __restrict__ meta,
    u16* __restrict__ H1, int p0, int p1)
{
    const int NCOL = HID / BN;                 // 32
    int nact = NCOL * meta[0];
    int bid = blockIdx.x;
    if (bid >= nact) return;
    int swz = xcd_swz(bid, nact);
    int tile = swz / NCOL, colb = swz & (NCOL - 1);
    u32 entry = table[tile];
    const int e = (int)(entry >> 20);
    const int row0 = (int)(entry & 0xFFFFFu);
    const int ce = cnt[e], oe = offs[e];
    if (oe + min(ce, row0 + BM) <= p0 || oe + row0 >= p1) return;
    const int col0 = colb * BN;

    GEMM_SHARED_DECLS

    const int tid = threadIdx.x;
    const int lane = tid & 63, wid = tid >> 6;
    const int wm = (wid >> 1) * 64, wn = (wid & 1) * 64;

    f32x4 acc[4][4] = {};

    const u16* Agp = xb;
    const u16* Bgp = W1b;
    // chunk 0: idx=tid, chunk 1: idx=256+tid
    int r0c = tid >> 2,          s0c = (tid & 3) ^ (r0c & 3);
    int r1c = (256 + tid) >> 2,  s1c = (tid & 3) ^ (r1c & 3);
    int g0 = row0 + r0c, g1 = row0 + r1c;
    int tk0 = (g0 < ce) ? tok[oe + g0] : tok[oe];
    int tk1 = (g1 < ce) ? tok[oe + g1] : tok[oe];
    size_t aoff0 = (size_t)tk0 * DMODEL + (size_t)(s0c * 8);
    size_t aoff1 = (size_t)tk1 * DMODEL + (size_t)(s1c * 8);
    size_t boff0 = ((size_t)e * HID + col0 + r0c) * DMODEL + (size_t)(s0c * 8);
    size_t boff1 = ((size_t)e * HID + col0 + r1c) * DMODEL + (size_t)(s1c * 8);

    PIPELINE_LOOP(DMODEL / BK);                // 32 K-steps

    float bias[4];
#pragma unroll
    for (int ni = 0; ni < 4; ++ni) bias[ni] = b1[e * HID + col0 + wn + ni * 16 + (lane & 15)];

#pragma unroll
    for (int mi = 0; mi < 4; ++mi) {
#pragma unroll
        for (int j = 0; j < 4; ++j) {
            int r = wm + mi * 16 + ((lane >> 4) * 4) + j;
            int gi = row0 + r;
            int p = oe + gi;
            if (gi < ce && p >= p0 && p < p1) {
                u16* hrow = H1 + (size_t)(p - p0) * HID;
#pragma unroll
                for (int ni = 0; ni < 4; ++ni) {
                    int n = col0 + wn + ni * 16 + (lane & 15);
                    hrow[n] = f2b(gelu_fast(acc[mi][ni][j] + bias[ni]));
                }
            }
        }
    }
}

// GEMM2: out[tok[p], d] += wgt[p] * ( sum_h H1[p, h] * W2b[e, d, h] + b2[e, d] )
__global__ __launch_bounds__(256) void gemm2_kernel(
    const u16* __restrict__ H1, const u16* __restrict__ W2b, const float* __restrict__ b2,
    const int* __restrict__ tok, const float* __restrict__ wgt,
    const int* __restrict__ cnt, const int* __restrict__ offs,
    const u32* __restrict__ table, const int* __restrict__ meta,
    float* __restrict__ out, int p0, int p1)
{
    const int NCOL = DMODEL / BN;              // 8
    int nact = NCOL * meta[0];
    int bid = blockIdx.x;
    if (bid >= nact) return;
    int swz = xcd_swz(bid, nact);
    int tile = swz / NCOL, colb = swz & (NCOL - 1);
    u32 entry = table[tile];
    const int e = (int)(entry >> 20);
    const int row0 = (int)(entry & 0xFFFFFu);
    const int ce = cnt[e], oe = offs[e];
    if (oe + min(ce, row0 + BM) <= p0 || oe + row0 >= p1) return;
    const int col0 = colb * BN;

    GEMM_SHARED_DECLS

    const int tid = threadIdx.x;
    const int lane = tid & 63, wid = tid >> 6;
    const int wm = (wid >> 1) * 64, wn = (wid & 1) * 64;

    f32x4 acc[4][4] = {};

    const u16* Agp = H1;
    const u16* Bgp = W2b;
    const int smax = p1 - p0 - 1;
    int r0c = tid >> 2,          s0c = (tid & 3) ^ (r0c & 3);
    int r1c = (256 + tid) >> 2,  s1c = (tid & 3) ^ (r1c & 3);
    int a0 = oe + row0 + r0c - p0;  a0 = a0 < 0 ? 0 : (a0 > smax ? smax : a0);
    int a1 = oe + row0 + r1c - p0;  a1 = a1 < 0 ? 0 : (a1 > smax ? smax : a1);
    size_t aoff0 = (size_t)a0 * HID + (size_t)(s0c * 8);
    size_t aoff1 = (size_t)a1 * HID + (size_t)(s1c * 8);
    size_t boff0 = ((size_t)e * DMODEL + col0 + r0c) * HID + (size_t)(s0c * 8);
    size_t boff1 = ((size_t)e * DMODEL + col0 + r1c) * HID + (size_t)(s1c * 8);

    PIPELINE_LOOP(HID / BK);                   // 128 K-steps

    float bias[4];
#pragma unroll
    for (int ni = 0; ni < 4; ++ni) bias[ni] = b2[e * DMODEL + col0 + wn + ni * 16 + (lane & 15)];

#pragma unroll
    for (int mi = 0; mi < 4; ++mi) {
#pragma unroll
        for (int j = 0; j < 4; ++j) {
            int r = wm + mi * 16 + ((lane >> 4) * 4) + j;
            int gi = row0 + r;
            int p = oe + gi;
            if (gi < ce && p >= p0 && p < p1) {
                float w = wgt[p];
                float* orow = out + (size_t)tok[p] * DMODEL;
#pragma unroll
                for (int ni = 0; ni < 4; ++ni) {
                    int n = col0 + wn + ni * 16 + (lane & 15);
                    atomicAdd(orow + n, w * (acc[mi][ni][j] + bias[ni]));
                }
            }
        }
    }
}

// ---------------- host launcher ----------------
extern "C" void kernel_launch(void* const* d_in, const int* in_sizes, int n_in,
                              void* d_out, int out_size, void* d_ws, size_t ws_size,
                              hipStream_t stream)
{
    const float* x  = (const float*)d_in[0];
    const float* Wr = (const float*)d_in[1];
    const float* br = (const float*)d_in[2];
    const float* W1 = (const float*)d_in[3];
    const float* b1 = (const float*)d_in[4];
    const float* W2 = (const float*)d_in[5];
    const float* b2 = (const float*)d_in[6];
    float* out = (float*)d_out;

    char* ws = (char*)d_ws;
    u16* xb = (u16*)ws;                               // 16 MiB
    size_t o2 = (size_t)T_TOK * DMODEL * 2;
    int*   cnt   = (int*)(ws + o2);
    int*   fill  = (int*)(ws + o2 + 64);
    int*   offs  = (int*)(ws + o2 + 128);
    int*   meta  = (int*)(ws + o2 + 192);
    u32*   table = (u32*)(ws + o2 + 256);             // <=136 entries
    int*   topi  = (int*)(ws + o2 + 2048);
    float* topw  = (float*)(ws + o2 + 2048 + (size_t)NPAIR * 4);
    int*   tok   = (int*)(ws + o2 + 2048 + (size_t)NPAIR * 8);
    float* wgt   = (float*)(ws + o2 + 2048 + (size_t)NPAIR * 12);

    const size_t WBYTES = (size_t)NEXP * DMODEL * HID * 2;   // 64 MiB each
    size_t oW2 = o2 + (2u << 20);
    size_t oW1 = oW2 + WBYTES;
    size_t oH  = oW1 + WBYTES;
    u16* W2b = (u16*)(ws + oW2);
    u16* W1b = (u16*)(ws + oW1);
    u16* H1  = (u16*)(ws + oH);

    long long cap = ((long long)ws_size - (long long)oH) / ((long long)HID * 2);
    int slice = cap >= NPAIR ? NPAIR : (cap < 1024 ? 1024 : (int)cap);

    hipMemsetAsync(out, 0, (size_t)out_size * 4, stream);
    hipMemsetAsync(cnt, 0, 256, stream);

    cvt_kernel<<<dim3(1024), 256, 0, stream>>>(x, xb, (long)T_TOK * DMODEL / 8);
    cvt_kernel<<<dim3(2048), 256, 0, stream>>>(W2, W2b, (long)NEXP * DMODEL * HID / 8);
    cvt_kernel<<<dim3(2048), 256, 0, stream>>>(W1, W1b, (long)NEXP * DMODEL * HID / 8);

    router_kernel<<<dim3(T_TOK / 4), 256, 0, stream>>>(x, Wr, br, topi, topw, cnt);
    offsets_kernel<<<dim3(1), 64, 0, stream>>>(cnt, offs, table, meta);
    scatter_kernel<<<dim3(T_TOK / 256), 256, 0, stream>>>(topi, topw, offs, fill, tok, wgt);

    for (int pp = 0; pp < NPAIR; pp += slice) {
        int p1v = pp + slice < NPAIR ? pp + slice : NPAIR;
        gemm1_kernel<<<dim3((HID / BN) * MAXT), 256, 0, stream>>>(
            xb, W1b, b1, tok, cnt, offs, table, meta, H1, pp, p1v);
        gemm2_kernel<<<dim3((DMODEL / BN) * MAXT), 256, 0, stream>>>(
            H1, W2b, b2, tok, wgt, cnt, offs, table, meta, out, pp, p1v);
    }
}

// Round 6
// 779.894 us; speedup vs baseline: 1.0593x; 1.0593x over previous
//
#include <hip/hip_runtime.h>

// ---- problem dims (fixed) ----
#define T_TOK 8192      // B*S
#define DMODEL 1024
#define NEXP 8
#define TOPK 2
#define HID 4096
#define NPAIR (T_TOK*TOPK)   // 16384
#define BM 256
#define BN 256
#define BK 64
#define MAXT (NPAIR/BM + NEXP)   // 72 row-tiles upper bound

typedef unsigned short u16;
typedef unsigned int u32;
typedef short s16x8 __attribute__((ext_vector_type(8)));
typedef float f32x4 __attribute__((ext_vector_type(4)));

// fp32 -> bf16 round-to-nearest-even
__device__ __forceinline__ u16 f2b(float f) {
    union { float f; unsigned int u; } v; v.f = f;
    return (u16)((v.u + 0x7fffu + ((v.u >> 16) & 1u)) >> 16);
}

__device__ __forceinline__ s16x8 cvt8(float4 f0, float4 f1) {
    s16x8 o;
    o[0]=(short)f2b(f0.x); o[1]=(short)f2b(f0.y); o[2]=(short)f2b(f0.z); o[3]=(short)f2b(f0.w);
    o[4]=(short)f2b(f1.x); o[5]=(short)f2b(f1.y); o[6]=(short)f2b(f1.z); o[7]=(short)f2b(f1.w);
    return o;
}

// async global->LDS, 16B per lane; LDS dest linear in lane order
__device__ __forceinline__ void gload16(const void* g, void* l) {
    __builtin_amdgcn_global_load_lds(
        (const __attribute__((address_space(1))) unsigned int*)g,
        (__attribute__((address_space(3))) unsigned int*)l, 16, 0, 0);
}

// tanh-form gelu, exp/rcp in HW
__device__ __forceinline__ float gelu_fast(float v) {
    float y = 0.7978845608028654f * v * fmaf(0.044715f * v, v, 1.0f);
    float t = -2.8853900817779268f * y;   // -2y * log2(e)
    float z, r;
    asm("v_exp_f32 %0, %1" : "=v"(z) : "v"(t));
    float den = 1.0f + z;
    asm("v_rcp_f32 %0, %1" : "=v"(r) : "v"(den));
    return v * r;
}

// m204 bijective XCD swizzle over nact active blocks
__device__ __forceinline__ int xcd_swz(int bid, int nact) {
    int q = nact >> 3, r = nact & 7;
    int xcd = bid & 7, i = bid >> 3;
    return (xcd < r ? xcd * (q + 1) : r * (q + 1) + (xcd - r) * q) + i;
}

// ---------------- fp32 -> bf16 conversion ----------------
__global__ __launch_bounds__(256) void cvt_kernel(const float* __restrict__ in,
                                                  u16* __restrict__ out, long n8) {
    long stride = (long)gridDim.x * 256;
    for (long i = (long)blockIdx.x * 256 + threadIdx.x; i < n8; i += stride) {
        const float4* p = (const float4*)(in + i * 8);
        float4 f0 = p[0], f1 = p[1];
        *(s16x8*)(out + i * 8) = cvt8(f0, f1);
    }
}

// ---------------- router (fp32; selection must match reference) ----------------
__global__ __launch_bounds__(256) void router_kernel(
    const float* __restrict__ x, const float* __restrict__ Wr, const float* __restrict__ br,
    int* __restrict__ topi, float* __restrict__ topw, int* __restrict__ cnt)
{
    __shared__ float WrS[NEXP * DMODEL];
    int tid = threadIdx.x;
    const float4* Wr4 = (const float4*)Wr;
    float4* WrS4 = (float4*)WrS;
    for (int i = tid; i < NEXP * DMODEL / 4; i += 256) WrS4[i] = Wr4[i];
    __syncthreads();

    int wid = tid >> 6, lane = tid & 63;
    int t = blockIdx.x * 4 + wid;
    const float* xr = x + (size_t)t * DMODEL;

    float acc[NEXP];
#pragma unroll
    for (int e = 0; e < NEXP; ++e) acc[e] = 0.f;
    for (int i = lane; i < DMODEL; i += 64) {
        float xv = xr[i];
#pragma unroll
        for (int e = 0; e < NEXP; ++e) acc[e] = fmaf(xv, WrS[e * DMODEL + i], acc[e]);
    }
#pragma unroll
    for (int e = 0; e < NEXP; ++e) {
        float v = acc[e];
#pragma unroll
        for (int off = 32; off > 0; off >>= 1) v += __shfl_xor(v, off);
        acc[e] = v;
    }
    if (lane == 0) {
        float lg[NEXP];
#pragma unroll
        for (int e = 0; e < NEXP; ++e) lg[e] = acc[e] + br[e];
        int i1 = 0;
#pragma unroll
        for (int e = 1; e < NEXP; ++e) if (lg[e] > lg[i1]) i1 = e;
        int i2 = (i1 == 0) ? 1 : 0;
#pragma unroll
        for (int e = 0; e < NEXP; ++e) if (e != i1 && lg[e] > lg[i2]) i2 = e;
        float e2 = expf(lg[i2] - lg[i1]);
        float s = 1.f + e2;
        topi[t * 2] = i1;  topi[t * 2 + 1] = i2;
        topw[t * 2] = 1.f / s;  topw[t * 2 + 1] = e2 / s;
        atomicAdd(&cnt[i1], 1);
        atomicAdd(&cnt[i2], 1);
    }
}

// offsets + compact tile table (BM=256) + tile count
__global__ void offsets_kernel(const int* __restrict__ cnt, int* __restrict__ offs,
                               u32* __restrict__ table, int* __restrict__ meta) {
    if (threadIdx.x == 0 && blockIdx.x == 0) {
        int a = 0;
        for (int e = 0; e < NEXP; ++e) { offs[e] = a; a += cnt[e]; }
        offs[NEXP] = a;
        int nt = 0;
        for (int e = 0; e < NEXP; ++e)
            for (int r0 = 0; r0 < cnt[e]; r0 += BM)
                table[nt++] = ((u32)e << 20) | (u32)r0;
        meta[0] = nt;
    }
}

// wave-aggregated scatter
__global__ __launch_bounds__(256) void scatter_kernel(
    const int* __restrict__ topi, const float* __restrict__ topw,
    const int* __restrict__ offs, int* __restrict__ fill,
    int* __restrict__ tok, float* __restrict__ wgt)
{
    int t = blockIdx.x * 256 + threadIdx.x;
    int lane = threadIdx.x & 63;
#pragma unroll
    for (int s = 0; s < TOPK; ++s) {
        int e = topi[t * 2 + s];
        float w = topw[t * 2 + s];
#pragma unroll
        for (int ex = 0; ex < NEXP; ++ex) {
            unsigned long long m = __ballot(e == ex);
            if (e == ex) {
                int ldr = (int)__ffsll((unsigned long long)m) - 1;
                int base = 0;
                if (lane == ldr) base = atomicAdd(&fill[ex], (int)__popcll(m));
                base = __shfl(base, ldr);
                int mypos = base + (int)__popcll(m & ((1ull << lane) - 1ull));
                int p = offs[ex] + mypos;
                tok[p] = t;
                wgt[p] = w;
            }
        }
    }
}

// ======== 256x256 multi-phase GEMM machinery ========
// LDS (u16 S[65536] = 128 KiB): per buffer cur (64 KiB): A half0 [0,16K)B,
// A half1 [16K,32K)B, B half0 [32K,48K)B, B half1 [48K,64K)B.
// Half-tile = 128 rows x 64 cols bf16, row = 128 B = 8 slots of 16 B,
// slot XOR (row&7) swizzle (proven conflict-free rounds 2-4).
#define LDS_A(c, h) ((char*)S + (c) * 65536 + (h) * 16384)
#define LDS_B(c, h) ((char*)S + (c) * 65536 + 32768 + (h) * 16384)

// stage one 128x64 half-tile: 2 x gload16 per thread (1024 chunks total)
#define STG(dstbase, gp, o0, o1, kt) do {                                   \
    gload16((gp) + (o0) + (size_t)(kt), (dstbase) + tid * 16);              \
    gload16((gp) + (o1) + (size_t)(kt), (dstbase) + 8192 + tid * 16);       \
} while (0)

#define LOAD_AV(c, mq, kk) do {                                             \
    const char* ab = LDS_A(c, wm);                                          \
    _Pragma("unroll") for (int i = 0; i < 4; ++i) {                         \
        int rr = (mq) * 64 + i * 16 + (lane & 15);                          \
        int sl = ((kk) * 4 + (lane >> 4)) ^ (rr & 7);                       \
        av[i] = *(const s16x8*)(ab + rr * 128 + sl * 16);                   \
    }                                                                       \
} while (0)

#define LOAD_BV(c, kk) do {                                                 \
    const char* bb = LDS_B(c, wn >> 1);                                     \
    _Pragma("unroll") for (int nf = 0; nf < 4; ++nf) {                      \
        int rb = (wn & 1) * 64 + nf * 16 + (lane & 15);                     \
        int sl = ((kk) * 4 + (lane >> 4)) ^ (rb & 7);                       \
        bv[nf] = *(const s16x8*)(bb + rb * 128 + sl * 16);                  \
    }                                                                       \
} while (0)

#define MFMA16(mq) do {                                                     \
    __builtin_amdgcn_s_setprio(1);                                          \
    _Pragma("unroll") for (int i = 0; i < 4; ++i)                           \
    _Pragma("unroll") for (int nf = 0; nf < 4; ++nf)                        \
        acc[(mq) * 4 + i][nf] = __builtin_amdgcn_mfma_f32_16x16x32_bf16(    \
            av[i], bv[nf], acc[(mq) * 4 + i][nf], 0, 0, 0);                 \
    __builtin_amdgcn_s_setprio(0);                                          \
} while (0)

#define BARX() do { __builtin_amdgcn_s_barrier(); asm volatile("" ::: "memory"); } while (0)
#define VMW0() asm volatile("s_waitcnt vmcnt(0)" ::: "memory")

#define PIPE_PROLOGUE() do {                                                \
    STG(LDS_A(0, 0), Agp, aoff00, aoff01, 0);                               \
    STG(LDS_A(0, 1), Agp, aoff10, aoff11, 0);                               \
    STG(LDS_B(0, 0), Bgp, boff00, boff01, 0);                               \
    STG(LDS_B(0, 1), Bgp, boff10, boff11, 0);                               \
    VMW0(); BARX();                                                         \
} while (0)

// 4 phases per K-tile: stage next tile's halves in phases 1-2 (>=2.5-phase
// latency cover), single vmcnt(0) per tile at phase 4. Stage targets buf^1
// whose last read was previous iteration (2 barriers back) -> race-free.
#define PIPE_LOOP(NT)                                                       \
    int cur = 0;                                                            \
    _Pragma("unroll 1")                                                     \
    for (int t = 0; t < (NT); ++t) {                                        \
        const int nk = (t + 1) * BK;                                        \
        const bool pre = (t + 1) < (NT);                                    \
        LOAD_AV(cur, 0, 0); LOAD_BV(cur, 0);                                \
        if (pre) { STG(LDS_A(cur ^ 1, 0), Agp, aoff00, aoff01, nk);         \
                   STG(LDS_A(cur ^ 1, 1), Agp, aoff10, aoff11, nk); }       \
        BARX(); MFMA16(0); BARX();                                          \
        LOAD_AV(cur, 1, 0);                                                 \
        if (pre) { STG(LDS_B(cur ^ 1, 0), Bgp, boff00, boff01, nk);         \
                   STG(LDS_B(cur ^ 1, 1), Bgp, boff10, boff11, nk); }       \
        BARX(); MFMA16(1); BARX();                                          \
        LOAD_AV(cur, 0, 1); LOAD_BV(cur, 1);                                \
        BARX(); MFMA16(0); BARX();                                          \
        LOAD_AV(cur, 1, 1);                                                 \
        BARX(); MFMA16(1);                                                  \
        VMW0();                                                             \
        BARX();                                                             \
        cur ^= 1;                                                           \
    }

// GEMM1: H1[p, n] = gelu( sum_d xb[tok[p], d] * W1b[e, n, d] + b1[e, n] )
__global__ __launch_bounds__(512, 2) void gemm1_kernel(
    const u16* __restrict__ xb, const u16* __restrict__ W1b, const float* __restrict__ b1,
    const int* __restrict__ tok, const int* __restrict__ cnt, const int* __restrict__ offs,
    const u32* __restrict__ table, const int* __restrict__ meta,
    u16* __restrict__ H1, int p0, int p1)
{
    const int NCOL = HID / BN;                 // 16
    int nact = NCOL * meta[0];
    int bid = blockIdx.x;
    if (bid >= nact) return;
    int swz = xcd_swz(bid, nact);
    int tile = swz / NCOL, colb = swz & (NCOL - 1);
    u32 entry = table[tile];
    const int e = (int)(entry >> 20);
    const int row0 = (int)(entry & 0xFFFFFu);
    const int ce = cnt[e], oe = offs[e];
    if (oe + min(ce, row0 + BM) <= p0 || oe + row0 >= p1) return;
    const int col0 = colb * BN;

    __shared__ __align__(16) u16 S[65536];     // 128 KiB

    const int tid = threadIdx.x;               // 0..511
    const int lane = tid & 63, wid = tid >> 6;
    const int wm = wid >> 2, wn = wid & 3;     // 2x4 wave grid; wave C = 128x64

    f32x4 acc[8][4] = {};
    s16x8 av[4], bv[4];

    const u16* Agp = xb;
    const u16* Bgp = W1b;
    int r0c = tid >> 3,        s0 = (tid & 7) ^ (r0c & 7);
    int r1c = 64 + (tid >> 3), s1 = (tid & 7) ^ (r1c & 7);
#define TOKA(h, rc) ((row0 + (h) * 128 + (rc)) < ce ? tok[oe + row0 + (h) * 128 + (rc)] : tok[oe])
    size_t aoff00 = (size_t)TOKA(0, r0c) * DMODEL + s0 * 8;
    size_t aoff01 = (size_t)TOKA(0, r1c) * DMODEL + s1 * 8;
    size_t aoff10 = (size_t)TOKA(1, r0c) * DMODEL + s0 * 8;
    size_t aoff11 = (size_t)TOKA(1, r1c) * DMODEL + s1 * 8;
#undef TOKA
    size_t boff00 = ((size_t)e * HID + col0 + r0c) * DMODEL + s0 * 8;
    size_t boff01 = ((size_t)e * HID + col0 + r1c) * DMODEL + s1 * 8;
    size_t boff10 = ((size_t)e * HID + col0 + 128 + r0c) * DMODEL + s0 * 8;
    size_t boff11 = ((size_t)e * HID + col0 + 128 + r1c) * DMODEL + s1 * 8;

    PIPE_PROLOGUE();
    PIPE_LOOP(DMODEL / BK)                     // 16 K-tiles

    float bias[4];
#pragma unroll
    for (int nf = 0; nf < 4; ++nf)
        bias[nf] = b1[e * HID + col0 + wn * 64 + nf * 16 + (lane & 15)];

#pragma unroll
    for (int mf = 0; mf < 8; ++mf) {
#pragma unroll
        for (int j = 0; j < 4; ++j) {
            int r = wm * 128 + mf * 16 + ((lane >> 4) * 4) + j;
            int gi = row0 + r;
            int p = oe + gi;
            if (gi < ce && p >= p0 && p < p1) {
                u16* hrow = H1 + (size_t)(p - p0) * HID;
#pragma unroll
                for (int nf = 0; nf < 4; ++nf) {
                    int n = col0 + wn * 64 + nf * 16 + (lane & 15);
                    hrow[n] = f2b(gelu_fast(acc[mf][nf][j] + bias[nf]));
                }
            }
        }
    }
}

// GEMM2: out[tok[p], d] += wgt[p] * ( sum_h H1[p, h] * W2b[e, d, h] + b2[e, d] )
__global__ __launch_bounds__(512, 2) void gemm2_kernel(
    const u16* __restrict__ H1, const u16* __restrict__ W2b, const float* __restrict__ b2,
    const int* __restrict__ tok, const float* __restrict__ wgt,
    const int* __restrict__ cnt, const int* __restrict__ offs,
    const u32* __restrict__ table, const int* __restrict__ meta,
    float* __restrict__ out, int p0, int p1)
{
    const int NCOL = DMODEL / BN;              // 4
    int nact = NCOL * meta[0];
    int bid = blockIdx.x;
    if (bid >= nact) return;
    int swz = xcd_swz(bid, nact);
    int tile = swz / NCOL, colb = swz & (NCOL - 1);
    u32 entry = table[tile];
    const int e = (int)(entry >> 20);
    const int row0 = (int)(entry & 0xFFFFFu);
    const int ce = cnt[e], oe = offs[e];
    if (oe + min(ce, row0 + BM) <= p0 || oe + row0 >= p1) return;
    const int col0 = colb * BN;

    __shared__ __align__(16) u16 S[65536];     // 128 KiB

    const int tid = threadIdx.x;
    const int lane = tid & 63, wid = tid >> 6;
    const int wm = wid >> 2, wn = wid & 3;

    f32x4 acc[8][4] = {};
    s16x8 av[4], bv[4];

    const u16* Agp = H1;
    const u16* Bgp = W2b;
    const int smax = p1 - p0 - 1;
    int r0c = tid >> 3,        s0 = (tid & 7) ^ (r0c & 7);
    int r1c = 64 + (tid >> 3), s1 = (tid & 7) ^ (r1c & 7);
#define AIDX(h, rc) ({ int ai_ = oe + row0 + (h) * 128 + (rc) - p0;          \
                       ai_ < 0 ? 0 : (ai_ > smax ? smax : ai_); })
    size_t aoff00 = (size_t)AIDX(0, r0c) * HID + s0 * 8;
    size_t aoff01 = (size_t)AIDX(0, r1c) * HID + s1 * 8;
    size_t aoff10 = (size_t)AIDX(1, r0c) * HID + s0 * 8;
    size_t aoff11 = (size_t)AIDX(1, r1c) * HID + s1 * 8;
#undef AIDX
    size_t boff00 = ((size_t)e * DMODEL + col0 + r0c) * HID + s0 * 8;
    size_t boff01 = ((size_t)e * DMODEL + col0 + r1c) * HID + s1 * 8;
    size_t boff10 = ((size_t)e * DMODEL + col0 + 128 + r0c) * HID + s0 * 8;
    size_t boff11 = ((size_t)e * DMODEL + col0 + 128 + r1c) * HID + s1 * 8;

    PIPE_PROLOGUE();
    PIPE_LOOP(HID / BK)                        // 64 K-tiles

    float bias[4];
#pragma unroll
    for (int nf = 0; nf < 4; ++nf)
        bias[nf] = b2[e * DMODEL + col0 + wn * 64 + nf * 16 + (lane & 15)];

#pragma unroll
    for (int mf = 0; mf < 8; ++mf) {
#pragma unroll
        for (int j = 0; j < 4; ++j) {
            int r = wm * 128 + mf * 16 + ((lane >> 4) * 4) + j;
            int gi = row0 + r;
            int p = oe + gi;
            if (gi < ce && p >= p0 && p < p1) {
                float w = wgt[p];
                float* orow = out + (size_t)tok[p] * DMODEL;
#pragma unroll
                for (int nf = 0; nf < 4; ++nf) {
                    int n = col0 + wn * 64 + nf * 16 + (lane & 15);
                    atomicAdd(orow + n, w * (acc[mf][nf][j] + bias[nf]));
                }
            }
        }
    }
}

// ---------------- host launcher ----------------
extern "C" void kernel_launch(void* const* d_in, const int* in_sizes, int n_in,
                              void* d_out, int out_size, void* d_ws, size_t ws_size,
                              hipStream_t stream)
{
    const float* x  = (const float*)d_in[0];
    const float* Wr = (const float*)d_in[1];
    const float* br = (const float*)d_in[2];
    const float* W1 = (const float*)d_in[3];
    const float* b1 = (const float*)d_in[4];
    const float* W2 = (const float*)d_in[5];
    const float* b2 = (const float*)d_in[6];
    float* out = (float*)d_out;

    char* ws = (char*)d_ws;
    u16* xb = (u16*)ws;                               // 16 MiB
    size_t o2 = (size_t)T_TOK * DMODEL * 2;
    int*   cnt   = (int*)(ws + o2);
    int*   fill  = (int*)(ws + o2 + 64);
    int*   offs  = (int*)(ws + o2 + 128);
    int*   meta  = (int*)(ws + o2 + 192);
    u32*   table = (u32*)(ws + o2 + 256);             // <=72 entries
    int*   topi  = (int*)(ws + o2 + 2048);
    float* topw  = (float*)(ws + o2 + 2048 + (size_t)NPAIR * 4);
    int*   tok   = (int*)(ws + o2 + 2048 + (size_t)NPAIR * 8);
    float* wgt   = (float*)(ws + o2 + 2048 + (size_t)NPAIR * 12);

    const size_t WBYTES = (size_t)NEXP * DMODEL * HID * 2;   // 64 MiB each
    size_t oW2 = o2 + (2u << 20);
    size_t oW1 = oW2 + WBYTES;
    size_t oH  = oW1 + WBYTES;
    u16* W2b = (u16*)(ws + oW2);
    u16* W1b = (u16*)(ws + oW1);
    u16* H1  = (u16*)(ws + oH);

    long long cap = ((long long)ws_size - (long long)oH) / ((long long)HID * 2);
    int slice = cap >= NPAIR ? NPAIR : (cap < 1024 ? 1024 : (int)cap);

    hipMemsetAsync(out, 0, (size_t)out_size * 4, stream);
    hipMemsetAsync(cnt, 0, 256, stream);

    cvt_kernel<<<dim3(1024), 256, 0, stream>>>(x, xb, (long)T_TOK * DMODEL / 8);
    cvt_kernel<<<dim3(2048), 256, 0, stream>>>(W2, W2b, (long)NEXP * DMODEL * HID / 8);
    cvt_kernel<<<dim3(2048), 256, 0, stream>>>(W1, W1b, (long)NEXP * DMODEL * HID / 8);

    router_kernel<<<dim3(T_TOK / 4), 256, 0, stream>>>(x, Wr, br, topi, topw, cnt);
    offsets_kernel<<<dim3(1), 64, 0, stream>>>(cnt, offs, table, meta);
    scatter_kernel<<<dim3(T_TOK / 256), 256, 0, stream>>>(topi, topw, offs, fill, tok, wgt);

    for (int pp = 0; pp < NPAIR; pp += slice) {
        int p1v = pp + slice < NPAIR ? pp + slice : NPAIR;
        gemm1_kernel<<<dim3((HID / BN) * MAXT), 512, 0, stream>>>(
            xb, W1b, b1, tok, cnt, offs, table, meta, H1, pp, p1v);
        gemm2_kernel<<<dim3((DMODEL / BN) * MAXT), 512, 0, stream>>>(
            H1, W2b, b2, tok, wgt, cnt, offs, table, meta, out, pp, p1v);
    }
}

// Round 7
// 774.216 us; speedup vs baseline: 1.0671x; 1.0073x over previous
//
#include <hip/hip_runtime.h>

// ---- problem dims (fixed) ----
#define T_TOK 8192      // B*S
#define DMODEL 1024
#define NEXP 8
#define TOPK 2
#define HID 4096
#define NPAIR (T_TOK*TOPK)   // 16384
#define BM 256
#define BN 256
#define BK 64
#define MAXT (NPAIR/BM + NEXP)   // 72 row-tiles upper bound

typedef unsigned short u16;
typedef unsigned int u32;
typedef short s16x8 __attribute__((ext_vector_type(8)));
typedef float f32x4 __attribute__((ext_vector_type(4)));

// fp32 -> bf16 round-to-nearest-even
__device__ __forceinline__ u16 f2b(float f) {
    union { float f; unsigned int u; } v; v.f = f;
    return (u16)((v.u + 0x7fffu + ((v.u >> 16) & 1u)) >> 16);
}

__device__ __forceinline__ s16x8 cvt8(float4 f0, float4 f1) {
    s16x8 o;
    o[0]=(short)f2b(f0.x); o[1]=(short)f2b(f0.y); o[2]=(short)f2b(f0.z); o[3]=(short)f2b(f0.w);
    o[4]=(short)f2b(f1.x); o[5]=(short)f2b(f1.y); o[6]=(short)f2b(f1.z); o[7]=(short)f2b(f1.w);
    return o;
}

// async global->LDS, 16B per lane; LDS dest linear in lane order
__device__ __forceinline__ void gload16(const void* g, void* l) {
    __builtin_amdgcn_global_load_lds(
        (const __attribute__((address_space(1))) unsigned int*)g,
        (__attribute__((address_space(3))) unsigned int*)l, 16, 0, 0);
}

// tanh-form gelu, exp/rcp in HW
__device__ __forceinline__ float gelu_fast(float v) {
    float y = 0.7978845608028654f * v * fmaf(0.044715f * v, v, 1.0f);
    float t = -2.8853900817779268f * y;   // -2y * log2(e)
    float z, r;
    asm("v_exp_f32 %0, %1" : "=v"(z) : "v"(t));
    float den = 1.0f + z;
    asm("v_rcp_f32 %0, %1" : "=v"(r) : "v"(den));
    return v * r;
}

// m204 bijective XCD swizzle over nact active blocks
__device__ __forceinline__ int xcd_swz(int bid, int nact) {
    int q = nact >> 3, r = nact & 7;
    int xcd = bid & 7, i = bid >> 3;
    return (xcd < r ? xcd * (q + 1) : r * (q + 1) + (xcd - r) * q) + i;
}

// ---------------- fp32 -> bf16 conversion ----------------
__global__ __launch_bounds__(256) void cvt_kernel(const float* __restrict__ in,
                                                  u16* __restrict__ out, long n8) {
    long stride = (long)gridDim.x * 256;
    for (long i = (long)blockIdx.x * 256 + threadIdx.x; i < n8; i += stride) {
        const float4* p = (const float4*)(in + i * 8);
        float4 f0 = p[0], f1 = p[1];
        *(s16x8*)(out + i * 8) = cvt8(f0, f1);
    }
}

// ---------------- router (fp32; selection must match reference) ----------------
__global__ __launch_bounds__(256) void router_kernel(
    const float* __restrict__ x, const float* __restrict__ Wr, const float* __restrict__ br,
    int* __restrict__ topi, float* __restrict__ topw, int* __restrict__ cnt)
{
    __shared__ float WrS[NEXP * DMODEL];
    int tid = threadIdx.x;
    const float4* Wr4 = (const float4*)Wr;
    float4* WrS4 = (float4*)WrS;
    for (int i = tid; i < NEXP * DMODEL / 4; i += 256) WrS4[i] = Wr4[i];
    __syncthreads();

    int wid = tid >> 6, lane = tid & 63;
    int t = blockIdx.x * 4 + wid;
    const float* xr = x + (size_t)t * DMODEL;

    float acc[NEXP];
#pragma unroll
    for (int e = 0; e < NEXP; ++e) acc[e] = 0.f;
    for (int i = lane; i < DMODEL; i += 64) {
        float xv = xr[i];
#pragma unroll
        for (int e = 0; e < NEXP; ++e) acc[e] = fmaf(xv, WrS[e * DMODEL + i], acc[e]);
    }
#pragma unroll
    for (int e = 0; e < NEXP; ++e) {
        float v = acc[e];
#pragma unroll
        for (int off = 32; off > 0; off >>= 1) v += __shfl_xor(v, off);
        acc[e] = v;
    }
    if (lane == 0) {
        float lg[NEXP];
#pragma unroll
        for (int e = 0; e < NEXP; ++e) lg[e] = acc[e] + br[e];
        int i1 = 0;
#pragma unroll
        for (int e = 1; e < NEXP; ++e) if (lg[e] > lg[i1]) i1 = e;
        int i2 = (i1 == 0) ? 1 : 0;
#pragma unroll
        for (int e = 0; e < NEXP; ++e) if (e != i1 && lg[e] > lg[i2]) i2 = e;
        float e2 = expf(lg[i2] - lg[i1]);
        float s = 1.f + e2;
        topi[t * 2] = i1;  topi[t * 2 + 1] = i2;
        topw[t * 2] = 1.f / s;  topw[t * 2 + 1] = e2 / s;
        atomicAdd(&cnt[i1], 1);
        atomicAdd(&cnt[i2], 1);
    }
}

// offsets + compact tile table (BM=256) + tile count
__global__ void offsets_kernel(const int* __restrict__ cnt, int* __restrict__ offs,
                               u32* __restrict__ table, int* __restrict__ meta) {
    if (threadIdx.x == 0 && blockIdx.x == 0) {
        int a = 0;
        for (int e = 0; e < NEXP; ++e) { offs[e] = a; a += cnt[e]; }
        offs[NEXP] = a;
        int nt = 0;
        for (int e = 0; e < NEXP; ++e)
            for (int r0 = 0; r0 < cnt[e]; r0 += BM)
                table[nt++] = ((u32)e << 20) | (u32)r0;
        meta[0] = nt;
    }
}

// wave-aggregated scatter
__global__ __launch_bounds__(256) void scatter_kernel(
    const int* __restrict__ topi, const float* __restrict__ topw,
    const int* __restrict__ offs, int* __restrict__ fill,
    int* __restrict__ tok, float* __restrict__ wgt)
{
    int t = blockIdx.x * 256 + threadIdx.x;
    int lane = threadIdx.x & 63;
#pragma unroll
    for (int s = 0; s < TOPK; ++s) {
        int e = topi[t * 2 + s];
        float w = topw[t * 2 + s];
#pragma unroll
        for (int ex = 0; ex < NEXP; ++ex) {
            unsigned long long m = __ballot(e == ex);
            if (e == ex) {
                int ldr = (int)__ffsll((unsigned long long)m) - 1;
                int base = 0;
                if (lane == ldr) base = atomicAdd(&fill[ex], (int)__popcll(m));
                base = __shfl(base, ldr);
                int mypos = base + (int)__popcll(m & ((1ull << lane) - 1ull));
                int p = offs[ex] + mypos;
                tok[p] = t;
                wgt[p] = w;
            }
        }
    }
}

// ======== 256x256 counted-vmcnt GEMM machinery ========
// LDS 128 KiB, per buffer c (64 KiB):
//   A half h (128 rows x 64 k, 128B rows, slot^(row&7) swizzle) at c*64K + h*16K
//   Bk kk  (256 rows x 32 k,  64B rows, slot = g^((row>>1)&3))  at c*64K + 32K + kk*16K
#define LDS_A(c, h)  ((char*)S + (c) * 65536 + (h) * 16384)
#define LDS_B(c, kk) ((char*)S + (c) * 65536 + 32768 + (kk) * 16384)

// stage one 16 KiB unit: 2 gloads/thread (2 per wave -> vmcnt counts 2/unit)
#define STG_A(dst, o0, o1, koff) do {                                       \
    gload16(Agp + (o0) + (size_t)(koff), (dst) + tid * 16);                 \
    gload16(Agp + (o1) + (size_t)(koff), (dst) + 8192 + tid * 16);          \
} while (0)
#define STG_B(dst, koff) do {                                               \
    gload16(Bgp + boffB0 + (size_t)(koff), (dst) + tid * 16);               \
    gload16(Bgp + boffB1 + (size_t)(koff), (dst) + 8192 + tid * 16);        \
} while (0)

#define LOAD_AV(c, mq, kk) do {                                             \
    const char* ab = LDS_A(c, wm);                                          \
    _Pragma("unroll") for (int i = 0; i < 4; ++i) {                         \
        int rr = (mq) * 64 + i * 16 + (lane & 15);                          \
        int sl = ((kk) * 4 + (lane >> 4)) ^ (rr & 7);                       \
        av[i] = *(const s16x8*)(ab + rr * 128 + sl * 16);                   \
    }                                                                       \
} while (0)

#define LOAD_BV(c, kk) do {                                                 \
    const char* bb = LDS_B(c, kk);                                          \
    _Pragma("unroll") for (int nf = 0; nf < 4; ++nf) {                      \
        int rb = wn * 64 + nf * 16 + (lane & 15);                           \
        int sl = (lane >> 4) ^ ((rb >> 1) & 3);                             \
        bv[nf] = *(const s16x8*)(bb + rb * 64 + sl * 16);                   \
    }                                                                       \
} while (0)

#define MFMA16(mq) do {                                                     \
    __builtin_amdgcn_s_setprio(1);                                          \
    _Pragma("unroll") for (int i = 0; i < 4; ++i)                           \
    _Pragma("unroll") for (int nf = 0; nf < 4; ++nf)                        \
        acc[(mq) * 4 + i][nf] = __builtin_amdgcn_mfma_f32_16x16x32_bf16(    \
            av[i], bv[nf], acc[(mq) * 4 + i][nf], 0, 0, 0);                 \
    __builtin_amdgcn_s_setprio(0);                                          \
} while (0)

#define BARX() do { __builtin_amdgcn_s_barrier(); asm volatile("" ::: "memory"); } while (0)
#define VM2() asm volatile("s_waitcnt vmcnt(2)" ::: "memory")
#define VM4() asm volatile("s_waitcnt vmcnt(4)" ::: "memory")
#define VM0() asm volatile("s_waitcnt vmcnt(0)" ::: "memory")

// Per tile t: stage order A0,A1,Bk0,Bk1 of tile t+1, 1 unit/phase.
// Per-wave outstanding-queue arithmetic (2 loads/unit):
//   enter P1: [A0 A1 Bk0 Bk1](t)=8; need first 3 units -> vmcnt(2)
//   enter P3: [Bk1(t), A0 A1 (t+1)]=6; need Bk1(t) -> vmcnt(4); last tile: vmcnt(0)
#define PIPE(NT, KBASE) do {                                                \
    int cur = 0;                                                            \
    { size_t k0 = (size_t)(KBASE);                                          \
      STG_A(LDS_A(0, 0), aoff00, aoff01, k0);                               \
      STG_A(LDS_A(0, 1), aoff10, aoff11, k0);                               \
      STG_B(LDS_B(0, 0), k0);                                               \
      STG_B(LDS_B(0, 1), k0 + 32); }                                        \
    _Pragma("unroll 1")                                                     \
    for (int t = 0; t < (NT); ++t) {                                        \
        const bool pre = (t + 1) < (NT);                                    \
        const size_t nk = (size_t)(KBASE) + (size_t)(t + 1) * BK;           \
        VM2(); BARX();                                                      \
        LOAD_AV(cur, 0, 0); LOAD_BV(cur, 0);                                \
        if (pre) STG_A(LDS_A(cur ^ 1, 0), aoff00, aoff01, nk);              \
        BARX(); MFMA16(0);                                                  \
        BARX();                                                             \
        LOAD_AV(cur, 1, 0);                                                 \
        if (pre) STG_A(LDS_A(cur ^ 1, 1), aoff10, aoff11, nk);              \
        BARX(); MFMA16(1);                                                  \
        if (pre) VM4(); else VM0();                                         \
        BARX();                                                             \
        LOAD_AV(cur, 0, 1); LOAD_BV(cur, 1);                                \
        if (pre) STG_B(LDS_B(cur ^ 1, 0), nk);                              \
        BARX(); MFMA16(0);                                                  \
        BARX();                                                             \
        LOAD_AV(cur, 1, 1);                                                 \
        if (pre) STG_B(LDS_B(cur ^ 1, 1), nk + 32);                         \
        BARX(); MFMA16(1);                                                  \
        cur ^= 1;                                                           \
    }                                                                       \
} while (0)

// common B-staging offset setup (row-split chunks of the k-split unit)
#define B_STAGE_OFFS(basecol, ldb) \
    int rB0 = tid >> 2,         sB0 = (tid & 3) ^ ((rB0 >> 1) & 3);         \
    int rB1 = (512 + tid) >> 2, sB1 = ((512 + tid) & 3) ^ ((rB1 >> 1) & 3); \
    size_t boffB0 = ((size_t)(basecol) + rB0) * (ldb) + sB0 * 8;            \
    size_t boffB1 = ((size_t)(basecol) + rB1) * (ldb) + sB1 * 8;

// GEMM1: H1[p, n] = gelu( sum_d xb[tok[p], d] * W1b[e, n, d] + b1[e, n] )
__global__ __launch_bounds__(512, 2) void gemm1_kernel(
    const u16* __restrict__ xb, const u16* __restrict__ W1b, const float* __restrict__ b1,
    const int* __restrict__ tok, const int* __restrict__ cnt, const int* __restrict__ offs,
    const u32* __restrict__ table, const int* __restrict__ meta,
    u16* __restrict__ H1, int p0, int p1)
{
    const int NCOL = HID / BN;                 // 16
    int nact = NCOL * meta[0];
    int bid = blockIdx.x;
    if (bid >= nact) return;
    int swz = xcd_swz(bid, nact);
    int tile = swz / NCOL, colb = swz & (NCOL - 1);
    u32 entry = table[tile];
    const int e = (int)(entry >> 20);
    const int row0 = (int)(entry & 0xFFFFFu);
    const int ce = cnt[e], oe = offs[e];
    if (oe + min(ce, row0 + BM) <= p0 || oe + row0 >= p1) return;
    const int col0 = colb * BN;

    __shared__ __align__(16) u16 S[65536];     // 128 KiB

    const int tid = threadIdx.x;               // 0..511
    const int lane = tid & 63, wid = tid >> 6;
    const int wm = wid >> 2, wn = wid & 3;     // 2x4 wave grid; wave C = 128x64

    f32x4 acc[8][4] = {};
    s16x8 av[4], bv[4];

    const u16* Agp = xb;
    const u16* Bgp = W1b;
    int r0c = tid >> 3,        s0 = (tid & 7) ^ (r0c & 7);
    int r1c = 64 + (tid >> 3), s1 = (tid & 7) ^ (r1c & 7);
#define TOKA(h, rc) ((row0 + (h) * 128 + (rc)) < ce ? tok[oe + row0 + (h) * 128 + (rc)] : tok[oe])
    size_t aoff00 = (size_t)TOKA(0, r0c) * DMODEL + s0 * 8;
    size_t aoff01 = (size_t)TOKA(0, r1c) * DMODEL + s1 * 8;
    size_t aoff10 = (size_t)TOKA(1, r0c) * DMODEL + s0 * 8;
    size_t aoff11 = (size_t)TOKA(1, r1c) * DMODEL + s1 * 8;
#undef TOKA
    B_STAGE_OFFS((size_t)e * HID + col0, DMODEL)

    PIPE(DMODEL / BK, 0);                      // 16 K-tiles

    float bias[4];
#pragma unroll
    for (int nf = 0; nf < 4; ++nf)
        bias[nf] = b1[e * HID + col0 + wn * 64 + nf * 16 + (lane & 15)];

#pragma unroll
    for (int mf = 0; mf < 8; ++mf) {
#pragma unroll
        for (int j = 0; j < 4; ++j) {
            int r = wm * 128 + mf * 16 + ((lane >> 4) * 4) + j;
            int gi = row0 + r;
            int p = oe + gi;
            if (gi < ce && p >= p0 && p < p1) {
                u16* hrow = H1 + (size_t)(p - p0) * HID;
#pragma unroll
                for (int nf = 0; nf < 4; ++nf) {
                    int n = col0 + wn * 64 + nf * 16 + (lane & 15);
                    hrow[n] = f2b(gelu_fast(acc[mf][nf][j] + bias[nf]));
                }
            }
        }
    }
}

// GEMM2 (K-split x2): out[tok[p], d] += wgt[p]*(sum_h H1[p,h]*W2b[e,d,h] + b2[e,d])
__global__ __launch_bounds__(512, 2) void gemm2_kernel(
    const u16* __restrict__ H1, const u16* __restrict__ W2b, const float* __restrict__ b2,
    const int* __restrict__ tok, const float* __restrict__ wgt,
    const int* __restrict__ cnt, const int* __restrict__ offs,
    const u32* __restrict__ table, const int* __restrict__ meta,
    float* __restrict__ out, int p0, int p1)
{
    const int NCOL = DMODEL / BN;              // 4
    int nact = NCOL * 2 * meta[0];
    int bid = blockIdx.x;
    if (bid >= nact) return;
    int swz = xcd_swz(bid, nact);
    int tile = swz >> 3;                       // / (NCOL*2)
    int rem = swz & 7;
    int colb = rem >> 1, khalf = rem & 1;
    u32 entry = table[tile];
    const int e = (int)(entry >> 20);
    const int row0 = (int)(entry & 0xFFFFFu);
    const int ce = cnt[e], oe = offs[e];
    if (oe + min(ce, row0 + BM) <= p0 || oe + row0 >= p1) return;
    const int col0 = colb * BN;
    const int kbase = khalf * (HID / 2);

    __shared__ __align__(16) u16 S[65536];     // 128 KiB

    const int tid = threadIdx.x;
    const int lane = tid & 63, wid = tid >> 6;
    const int wm = wid >> 2, wn = wid & 3;

    f32x4 acc[8][4] = {};
    s16x8 av[4], bv[4];

    const u16* Agp = H1;
    const u16* Bgp = W2b;
    const int smax = p1 - p0 - 1;
    int r0c = tid >> 3,        s0 = (tid & 7) ^ (r0c & 7);
    int r1c = 64 + (tid >> 3), s1 = (tid & 7) ^ (r1c & 7);
#define AIDX(h, rc) ({ int ai_ = oe + row0 + (h) * 128 + (rc) - p0;          \
                       ai_ < 0 ? 0 : (ai_ > smax ? smax : ai_); })
    size_t aoff00 = (size_t)AIDX(0, r0c) * HID + s0 * 8;
    size_t aoff01 = (size_t)AIDX(0, r1c) * HID + s1 * 8;
    size_t aoff10 = (size_t)AIDX(1, r0c) * HID + s0 * 8;
    size_t aoff11 = (size_t)AIDX(1, r1c) * HID + s1 * 8;
#undef AIDX
    B_STAGE_OFFS((size_t)e * DMODEL + col0, HID)

    PIPE(HID / 2 / BK, kbase);                 // 32 K-tiles

    float bias[4];
#pragma unroll
    for (int nf = 0; nf < 4; ++nf)
        bias[nf] = (khalf == 0)
            ? b2[e * DMODEL + col0 + wn * 64 + nf * 16 + (lane & 15)] : 0.0f;

#pragma unroll
    for (int mf = 0; mf < 8; ++mf) {
#pragma unroll
        for (int j = 0; j < 4; ++j) {
            int r = wm * 128 + mf * 16 + ((lane >> 4) * 4) + j;
            int gi = row0 + r;
            int p = oe + gi;
            if (gi < ce && p >= p0 && p < p1) {
                float w = wgt[p];
                float* orow = out + (size_t)tok[p] * DMODEL;
#pragma unroll
                for (int nf = 0; nf < 4; ++nf) {
                    int n = col0 + wn * 64 + nf * 16 + (lane & 15);
                    atomicAdd(orow + n, w * (acc[mf][nf][j] + bias[nf]));
                }
            }
        }
    }
}

// ---------------- host launcher ----------------
extern "C" void kernel_launch(void* const* d_in, const int* in_sizes, int n_in,
                              void* d_out, int out_size, void* d_ws, size_t ws_size,
                              hipStream_t stream)
{
    const float* x  = (const float*)d_in[0];
    const float* Wr = (const float*)d_in[1];
    const float* br = (const float*)d_in[2];
    const float* W1 = (const float*)d_in[3];
    const float* b1 = (const float*)d_in[4];
    const float* W2 = (const float*)d_in[5];
    const float* b2 = (const float*)d_in[6];
    float* out = (float*)d_out;

    char* ws = (char*)d_ws;
    u16* xb = (u16*)ws;                               // 16 MiB
    size_t o2 = (size_t)T_TOK * DMODEL * 2;
    int*   cnt   = (int*)(ws + o2);
    int*   fill  = (int*)(ws + o2 + 64);
    int*   offs  = (int*)(ws + o2 + 128);
    int*   meta  = (int*)(ws + o2 + 192);
    u32*   table = (u32*)(ws + o2 + 256);             // <=72 entries
    int*   topi  = (int*)(ws + o2 + 2048);
    float* topw  = (float*)(ws + o2 + 2048 + (size_t)NPAIR * 4);
    int*   tok   = (int*)(ws + o2 + 2048 + (size_t)NPAIR * 8);
    float* wgt   = (float*)(ws + o2 + 2048 + (size_t)NPAIR * 12);

    const size_t WBYTES = (size_t)NEXP * DMODEL * HID * 2;   // 64 MiB each
    size_t oW2 = o2 + (2u << 20);
    size_t oW1 = oW2 + WBYTES;
    size_t oH  = oW1 + WBYTES;
    u16* W2b = (u16*)(ws + oW2);
    u16* W1b = (u16*)(ws + oW1);
    u16* H1  = (u16*)(ws + oH);

    long long cap = ((long long)ws_size - (long long)oH) / ((long long)HID * 2);
    int slice = cap >= NPAIR ? NPAIR : (cap < 1024 ? 1024 : (int)cap);

    hipMemsetAsync(out, 0, (size_t)out_size * 4, stream);
    hipMemsetAsync(cnt, 0, 256, stream);

    cvt_kernel<<<dim3(1024), 256, 0, stream>>>(x, xb, (long)T_TOK * DMODEL / 8);
    cvt_kernel<<<dim3(4096), 256, 0, stream>>>(W2, W2b, (long)NEXP * DMODEL * HID / 8);
    cvt_kernel<<<dim3(4096), 256, 0, stream>>>(W1, W1b, (long)NEXP * DMODEL * HID / 8);

    router_kernel<<<dim3(T_TOK / 4), 256, 0, stream>>>(x, Wr, br, topi, topw, cnt);
    offsets_kernel<<<dim3(1), 64, 0, stream>>>(cnt, offs, table, meta);
    scatter_kernel<<<dim3(T_TOK / 256), 256, 0, stream>>>(topi, topw, offs, fill, tok, wgt);

    for (int pp = 0; pp < NPAIR; pp += slice) {
        int p1v = pp + slice < NPAIR ? pp + slice : NPAIR;
        gemm1_kernel<<<dim3((HID / BN) * MAXT), 512, 0, stream>>>(
            xb, W1b, b1, tok, cnt, offs, table, meta, H1, pp, p1v);
        gemm2_kernel<<<dim3((DMODEL / BN) * MAXT * 2), 512, 0, stream>>>(
            H1, W2b, b2, tok, wgt, cnt, offs, table, meta, out, pp, p1v);
    }
}